// Round 5
// baseline (67692.114 us; speedup 1.0000x reference)
//
#include <hip/hip_runtime.h>

#define BLOCK 512
#define GRID  256          // = #CUs; 152KB LDS => 1 block/CU => plain launch co-resident
#define PPT   4            // GRID*BLOCK*PPT = 524288 >= N
#define V     8            // DIMS/4 float4s per row
#define V3    3            // float4s of point 3 parked in LDS (rest in AGPRs)
#define DIMS  32
#define SLOTS_PER_THREAD (GRID / 64)   // wave-0 gather: 4 slots per lane

// ---- explicit AGPR residency (round-4 win: FETCH 30.4GB -> 1.9GB) -----------
// The allocator splits the unified file 128 arch + 128 acc and spills overflow
// ARRAYS to memory scratch instead of the idle AGPR half. These helpers pin
// values into AGPRs. volatile: LICM must not hoist the reads back out of the
// step loop (that would re-inflate arch pressure and re-spill).
__device__ __forceinline__ float to_agpr(float v) {
    float r;
    asm volatile("v_accvgpr_write_b32 %0, %1" : "=a"(r) : "v"(v));
    return r;
}
__device__ __forceinline__ float from_agpr(float a) {
    float r;
    asm volatile("v_accvgpr_read_b32 %0, %1" : "=v"(r) : "a"(a));
    return r;
}

// Monotone map: smaller float -> smaller u32 key (ties broken by index).
__device__ __forceinline__ unsigned pack_f32(float v) {
    unsigned u = __float_as_uint(v);
    return (u & 0x80000000u) ? ~u : (u | 0x80000000u);
}

__device__ __forceinline__ unsigned long long pack_min(float v, unsigned idx) {
    return ((unsigned long long)pack_f32(v) << 32) | (unsigned long long)idx;
}

__device__ __forceinline__ unsigned long long shfl_down_u64(unsigned long long v, int off) {
    unsigned lo = (unsigned)(v & 0xffffffffu);
    unsigned hi = (unsigned)(v >> 32);
    lo = __shfl_down(lo, off, 64);
    hi = __shfl_down(hi, off, 64);
    return ((unsigned long long)hi << 32) | (unsigned long long)lo;
}

// Butterfly: ALL 64 lanes end with the wave-wide min.
__device__ __forceinline__ unsigned long long shfl_xor_u64(unsigned long long v, int mask) {
    unsigned lo = (unsigned)(v & 0xffffffffu);
    unsigned hi = (unsigned)(v >> 32);
    lo = __shfl_xor(lo, mask, 64);
    hi = __shfl_xor(hi, mask, 64);
    return ((unsigned long long)hi << 32) | (unsigned long long)lo;
}

// Post this block's min for step t. Slot key: [val:32 | step:12 | idx:20].
// Caller guarantees threadIdx.x == 0.
__device__ __forceinline__ void post_slot(unsigned long long* __restrict__ slots,
                                          unsigned long long blockmin, int t,
                                          int bid) {
    const unsigned long long val = blockmin >> 32;
    const unsigned long long idx = blockmin & 0xFFFFFull;   // all idx < 2^20
    const unsigned long long key =
        (val << 32) | ((unsigned long long)((unsigned)t & 0xFFFu) << 20) | idx;
    __hip_atomic_store(&slots[(size_t)(t & 1) * GRID + bid], key,
                       __ATOMIC_RELAXED, __HIP_MEMORY_SCOPE_AGENT);
}

// Wave 0 polls all GRID slots for step t; returns the grid min to ALL 64 lanes
// (butterfly). Caller is wave 0 only.
// Safety of the 2-buffer reuse: thread 0 posts t+2 (same parity as t) only
// after its wave completed gather(t+1); every t+1 post's author (its thread 0)
// had itself finished reading every step-t slot before posting t+1 — so no
// step-t slot is overwritten before all reads.
__device__ __forceinline__ unsigned long long wave0_poll(
    const unsigned long long* __restrict__ slotp, int t) {
    const unsigned want = (unsigned)t & 0xFFFu;
    unsigned long long k[SLOTS_PER_THREAD];
    for (;;) {
        #pragma unroll
        for (int s = 0; s < SLOTS_PER_THREAD; ++s)
            k[s] = __hip_atomic_load(&slotp[threadIdx.x + 64 * s],
                                     __ATOMIC_RELAXED, __HIP_MEMORY_SCOPE_AGENT);
        bool ok = true;
        #pragma unroll
        for (int s = 0; s < SLOTS_PER_THREAD; ++s)
            ok &= (((unsigned)(k[s] >> 20) & 0xFFFu) == want);
        if (ok) break;
    }
    unsigned long long lb = k[0];
    #pragma unroll
    for (int s = 1; s < SLOTS_PER_THREAD; ++s)
        if (k[s] < lb) lb = k[s];
    #pragma unroll
    for (int mask = 32; mask >= 1; mask >>= 1) {
        unsigned long long o = shfl_xor_u64(lb, mask);
        lb = (o < lb) ? o : lb;
    }
    return lb;
}

// waves_per_eu(2,2): 2 waves/SIMD (the LDS cap enforces 1 block/CU anyway)
// => 256-register TOTAL budget per wave (arch + acc halves of the unified file).
__global__
__attribute__((amdgpu_flat_work_group_size(512, 512),
               amdgpu_waves_per_eu(2, 2)))
void stein_thin_persist(
    const float* __restrict__ x, const float* __restrict__ log_p,
    const float* __restrict__ score_p, const float* __restrict__ laplace,
    const float* __restrict__ ls_ptr, int* __restrict__ out,
    unsigned long long* __restrict__ slots, int N, int m)
{
    const int tid = blockIdx.x * BLOCK + threadIdx.x;
    const int T = GRID * BLOCK;          // 131072
    const int lane = threadIdx.x & 63;
    const int wave = threadIdx.x >> 6;

    const float ell = ls_ptr[0];
    const float ell2 = ell * ell;
    const bool unit = (ell2 == 1.0f);    // x/1.0f == x exactly (IEEE) => fast
                                         // path is bit-identical, general path kept
    const float w = 1.0f / (float)m;                 // weight_entropy = 1/m
    const float dim_over_ell2 = (float)DIMS / ell2;

    const float4* __restrict__ X4 = (const float4*)x;
    const float4* __restrict__ S4 = (const float4*)score_p;

    // LDS: tier A 128 KB + tier B 24 KB + pivot/reduce ~0.5 KB (conflict-free
    // transposed layout, SQ_LDS_BANK_CONFLICT = 0 verified).
    __shared__ float4 s_ldsT[V][2 * BLOCK];   // S-rows of points 0,1 (128 KB)
    __shared__ float4 s_lds3[V3][BLOCK];      // first 3 float4s of point 3 (24 KB)
    __shared__ float4 xi4[V];
    __shared__ float4 si4[V];
    __shared__ unsigned long long gmin_sh;
    __shared__ unsigned long long red_scratch[BLOCK / 64];

    // -------- persistent per-thread state ------------------------------------
    // arch VGPRs (<=128): xr0,xr1 (64) + objr/lpr (8) + workspace
    // AGPRs (116/128):    ax2,ax3 (x-rows of points 2,3) + as2 + as3 tail
    // LDS: S-rows of points 0,1 + first 3 float4s of point 3
    // => step loop has ZERO global data traffic and ZERO scratch traffic.
    float4 xr0[V];
    float4 xr1[V];
    float ax2[DIMS], ax3[DIMS];          // AGPR-resident (all indices constant)
    float as2[DIMS], as3[(V - V3) * 4];  // AGPR-resident
    float objr[PPT], lpr[PPT];

    {
        unsigned long long lbest = ~0ULL;
        #pragma unroll
        for (int p = 0; p < PPT; ++p) {
            const int j = tid + p * T;
            const bool act = (j < N);
            const int jc = act ? j : (N - 1);        // clamp: loads stay in-bounds
            const size_t base = (size_t)jc * V;
            float ss = 0.0f;
            #pragma unroll
            for (int v = 0; v < V; ++v) {
                const float4 s = S4[base + v];
                if (p < 2) s_ldsT[v][p * BLOCK + threadIdx.x] = s;
                if (p == 2) {
                    as2[4 * v + 0] = to_agpr(s.x); as2[4 * v + 1] = to_agpr(s.y);
                    as2[4 * v + 2] = to_agpr(s.z); as2[4 * v + 3] = to_agpr(s.w);
                }
                if (p == 3) {
                    if (v < V3) s_lds3[v][threadIdx.x] = s;
                    else {
                        const int b = (v - V3) * 4;
                        as3[b + 0] = to_agpr(s.x); as3[b + 1] = to_agpr(s.y);
                        as3[b + 2] = to_agpr(s.z); as3[b + 3] = to_agpr(s.w);
                    }
                }
                const float4 xx = X4[base + v];
                if (p == 0) xr0[v] = xx;
                else if (p == 1) xr1[v] = xx;
                else if (p == 2) {
                    ax2[4 * v + 0] = to_agpr(xx.x); ax2[4 * v + 1] = to_agpr(xx.y);
                    ax2[4 * v + 2] = to_agpr(xx.z); ax2[4 * v + 3] = to_agpr(xx.w);
                } else {
                    ax3[4 * v + 0] = to_agpr(xx.x); ax3[4 * v + 1] = to_agpr(xx.y);
                    ax3[4 * v + 2] = to_agpr(xx.z); ax3[4 * v + 3] = to_agpr(xx.w);
                }
                ss += s.x * s.x; ss += s.y * s.y; ss += s.z * s.z; ss += s.w * s.w;
            }
            lpr[p] = log_p[jc];
            // identical source shape to the previously verified kernels:
            float o = ((dim_over_ell2 + ss) + laplace[jc]) - w * log_p[jc];
            if (!act) o = __int_as_float(0x7F800000);   // +inf: never selected
            objr[p] = o;
            const unsigned long long pk = pack_min(o, (unsigned)j);
            if (pk < lbest) lbest = pk;
        }
        // wave min -> scratch; one barrier (also fences the LDS staging);
        // thread 0 alone finishes the block min and posts.
        #pragma unroll
        for (int off = 32; off >= 1; off >>= 1) {
            unsigned long long o = shfl_down_u64(lbest, off);
            lbest = (o < lbest) ? o : lbest;
        }
        if (lane == 0) red_scratch[wave] = lbest;
        __syncthreads();                                   // B1(0)
        if (threadIdx.x == 0) {
            unsigned long long r = red_scratch[0];
            #pragma unroll
            for (int i = 1; i < (BLOCK / 64); ++i) {
                unsigned long long o = red_scratch[i];
                r = (o < r) ? o : r;
            }
            post_slot(slots, r, 0, blockIdx.x);
        }
    }

    // -------- steps 1..m-1: 2 barriers per step ------------------------------
    // wave0: poll(t-1) -> butterfly min -> stage pivot -> gmin_sh   | B2
    // all:   read gmin_sh, compute update, wave min -> scratch      | B1
    // thread0: block min -> post(t)
    // Removed barriers are each covered by B1/B2 of the adjacent phase:
    // scratch, gmin_sh, xi4/si4 writers are all separated from their readers
    // by at least one remaining barrier (checked per-buffer).
    for (int t = 1; t < m; ++t) {
        if (threadIdx.x < 64) {
            const unsigned long long lb =
                wave0_poll(slots + (size_t)((t - 1) & 1) * GRID, t - 1);
            const int idx = (int)(lb & 0xFFFFFull);
            if (threadIdx.x < 16) {
                const size_t pb = (size_t)idx * V;
                if (threadIdx.x < 8) xi4[threadIdx.x] = X4[pb + threadIdx.x];
                else                 si4[threadIdx.x - 8] = S4[pb + (threadIdx.x - 8)];
            }
            if (threadIdx.x == 0) gmin_sh = lb;
        }
        __syncthreads();                                   // B2
        {
            const int idx = (int)(gmin_sh & 0xFFFFFull);
            if (blockIdx.x == 0 && threadIdx.x == 0) out[t - 1] = idx;
        }

        // outer-p / inner-v: FP summation order per accumulator is bit-identical
        // to the verified round-0/4 kernels.
        unsigned long long lbest = ~0ULL;
        #pragma unroll
        for (int p = 0; p < PPT; ++p) {
            float r2 = 0.0f, c1 = 0.0f, c2 = 0.0f, dss = 0.0f;
            #pragma unroll
            for (int v = 0; v < V; ++v) {
                const float4 xp = xi4[v];
                const float4 sp = si4[v];
                float4 xv, sv;
                if (p == 0)      { xv = xr0[v]; sv = s_ldsT[v][threadIdx.x]; }
                else if (p == 1) { xv = xr1[v]; sv = s_ldsT[v][BLOCK + threadIdx.x]; }
                else if (p == 2) {
                    xv.x = from_agpr(ax2[4 * v + 0]); xv.y = from_agpr(ax2[4 * v + 1]);
                    xv.z = from_agpr(ax2[4 * v + 2]); xv.w = from_agpr(ax2[4 * v + 3]);
                    sv.x = from_agpr(as2[4 * v + 0]); sv.y = from_agpr(as2[4 * v + 1]);
                    sv.z = from_agpr(as2[4 * v + 2]); sv.w = from_agpr(as2[4 * v + 3]);
                } else {
                    xv.x = from_agpr(ax3[4 * v + 0]); xv.y = from_agpr(ax3[4 * v + 1]);
                    xv.z = from_agpr(ax3[4 * v + 2]); xv.w = from_agpr(ax3[4 * v + 3]);
                    if (v < V3) sv = s_lds3[v][threadIdx.x];
                    else {
                        const int b = (v - V3) * 4;
                        sv.x = from_agpr(as3[b + 0]); sv.y = from_agpr(as3[b + 1]);
                        sv.z = from_agpr(as3[b + 2]); sv.w = from_agpr(as3[b + 3]);
                    }
                }
                float d;
                d = xp.x - xv.x; r2 += d * d; c1 += d * sp.x; c2 += sv.x * d; dss += sv.x * sp.x;
                d = xp.y - xv.y; r2 += d * d; c1 += d * sp.y; c2 += sv.y * d; dss += sv.y * sp.y;
                d = xp.z - xv.z; r2 += d * d; c1 += d * sp.z; c2 += sv.z * d; dss += sv.z * sp.z;
                d = xp.w - xv.w; r2 += d * d; c1 += d * sp.w; c2 += sv.w * d; dss += sv.w * sp.w;
            }
            // unit-ell2 fast path: division by 1.0f is an exact identity, so
            // both paths produce bit-identical values; general path preserved.
            float q, cross, tq;
            if (unit) {
                q = 1.0f + r2;
                cross = (c1 - c2);
                tq = 3.0f * r2;
            } else {
                q = 1.0f + r2 / ell2;
                cross = (c1 - c2) / ell2;
                tq = 3.0f * r2 / (ell2 * ell2);
            }
            const float qi  = 1.0f / q;
            const float sq  = sqrtf(qi);        // q^-0.5
            const float g   = qi * sq;          // q^-1.5
            const float q25 = qi * qi * sq;     // q^-2.5
            const float k = ((dim_over_ell2 * g - tq * q25) + cross * g) + dss * sq;
            // +inf rows stay +inf (their loads were clamped to a real row => k finite)
            const float o = objr[p] + (2.0f * k - w * lpr[p]);
            objr[p] = o;
            const unsigned long long pk = pack_min(o, (unsigned)(tid + p * T));
            if (pk < lbest) lbest = pk;
        }

        #pragma unroll
        for (int off = 32; off >= 1; off >>= 1) {
            unsigned long long o = shfl_down_u64(lbest, off);
            lbest = (o < lbest) ? o : lbest;
        }
        if (lane == 0) red_scratch[wave] = lbest;
        __syncthreads();                                   // B1
        if (threadIdx.x == 0) {
            unsigned long long r = red_scratch[0];
            #pragma unroll
            for (int i = 1; i < (BLOCK / 64); ++i) {
                unsigned long long o = red_scratch[i];
                r = (o < r) ? o : r;
            }
            post_slot(slots, r, t, blockIdx.x);
        }
    }

    // -------- final argmin -> out[m-1] ----------------------------------------
    {
        if (threadIdx.x < 64) {
            const unsigned long long lb =
                wave0_poll(slots + (size_t)((m - 1) & 1) * GRID, m - 1);
            if (threadIdx.x == 0) gmin_sh = lb;
        }
        __syncthreads();
        if (blockIdx.x == 0 && threadIdx.x == 0)
            out[m - 1] = (int)(gmin_sh & 0xFFFFFull);
    }
}

extern "C" void kernel_launch(void* const* d_in, const int* in_sizes, int n_in,
                              void* d_out, int out_size, void* d_ws, size_t ws_size,
                              hipStream_t stream) {
    const float* x        = (const float*)d_in[0];
    const float* log_p    = (const float*)d_in[1];
    const float* score_p  = (const float*)d_in[2];
    const float* laplace  = (const float*)d_in[3];
    const float* ls_ptr   = (const float*)d_in[4];

    int* out = (int*)d_out;
    int N = in_sizes[1];            // log_p has N elements
    int m = out_size;

    unsigned long long* slots = (unsigned long long*)d_ws;  // 2*GRID u64 = 4 KB

    // Single deterministic path: plain launch, identical on every call
    // (correctness call, graph capture, tripwire). 152 KB LDS => exactly
    // 1 block/CU => 256 blocks on 256 CUs are structurally co-resident.
    stein_thin_persist<<<dim3(GRID), dim3(BLOCK), 0, stream>>>(
        x, log_p, score_p, laplace, ls_ptr, out, slots, N, m);
}

// Round 6
// 19269.205 us; speedup vs baseline: 3.5130x; 3.5130x over previous
//
#include <hip/hip_runtime.h>

#define BLOCK 512
#define GRID  256          // = #CUs; 152KB LDS => 1 block/CU => plain launch co-resident
#define PPT   4            // GRID*BLOCK*PPT = 524288 >= N
#define V     8            // DIMS/4 float4s per row
#define V3    3            // float4s of point 3 parked in LDS (rest in AGPRs)
#define DIMS  32
#define SLOTS_PER_THREAD (GRID / 64)   // wave-0 gather: 4 slots per lane

// ---- explicit AGPR residency (round-4 win: FETCH 30.4GB -> 1.9GB) -----------
// The allocator splits the unified file 128 arch + 128 acc and spills overflow
// ARRAYS to memory scratch instead of the idle AGPR half. These helpers pin
// values into AGPRs. volatile: LICM must not hoist the reads back out of the
// step loop (that would re-inflate arch pressure and re-spill).
__device__ __forceinline__ float to_agpr(float v) {
    float r;
    asm volatile("v_accvgpr_write_b32 %0, %1" : "=a"(r) : "v"(v));
    return r;
}
__device__ __forceinline__ float from_agpr(float a) {
    float r;
    asm volatile("v_accvgpr_read_b32 %0, %1" : "=v"(r) : "a"(a));
    return r;
}

// Monotone map: smaller float -> smaller u32 key (ties broken by index).
__device__ __forceinline__ unsigned pack_f32(float v) {
    unsigned u = __float_as_uint(v);
    return (u & 0x80000000u) ? ~u : (u | 0x80000000u);
}

__device__ __forceinline__ unsigned long long pack_min(float v, unsigned idx) {
    return ((unsigned long long)pack_f32(v) << 32) | (unsigned long long)idx;
}

__device__ __forceinline__ unsigned long long shfl_down_u64(unsigned long long v, int off) {
    unsigned lo = (unsigned)(v & 0xffffffffu);
    unsigned hi = (unsigned)(v >> 32);
    lo = __shfl_down(lo, off, 64);
    hi = __shfl_down(hi, off, 64);
    return ((unsigned long long)hi << 32) | (unsigned long long)lo;
}

// Full-block min reduction; every thread returns the block-wide min.
// (round-4 verified form: 2 barriers)
__device__ __forceinline__ unsigned long long block_min_reduce(unsigned long long v,
                                                              unsigned long long* scratch) {
    #pragma unroll
    for (int off = 32; off >= 1; off >>= 1) {
        unsigned long long o = shfl_down_u64(v, off);
        v = (o < v) ? o : v;
    }
    const int wave = threadIdx.x >> 6;
    const int lane = threadIdx.x & 63;
    if (lane == 0) scratch[wave] = v;
    __syncthreads();
    unsigned long long r = scratch[0];
    #pragma unroll
    for (int i = 1; i < (BLOCK / 64); ++i) {
        unsigned long long o = scratch[i];
        r = (o < r) ? o : r;
    }
    __syncthreads();  // scratch safe for reuse
    return r;
}

// Post this block's min for step t. Slot key: [val:32 | step:12 | idx:20].
__device__ __forceinline__ void post_slot(unsigned long long* __restrict__ slots,
                                          unsigned long long blockmin, int t) {
    if (threadIdx.x == 0) {
        const unsigned long long val = blockmin >> 32;
        const unsigned long long idx = blockmin & 0xFFFFFull;   // all idx < 2^20
        const unsigned long long key =
            (val << 32) | ((unsigned long long)((unsigned)t & 0xFFFu) << 20) | idx;
        __hip_atomic_store(&slots[(size_t)(t & 1) * GRID + blockIdx.x], key,
                           __ATOMIC_RELAXED, __HIP_MEMORY_SCOPE_AGENT);
    }
}

// Wave 0 polls all GRID slots for step t; other waves wait at the barrier with
// zero memory traffic. Returns grid-wide min to ALL threads.
// (round-4 verified form: 2 barriers)
// Safety of the 2-buffer reuse: a block posts t+2 (same parity as t) only after
// gathering all t+1 posts, each of which required its author to finish reading
// every step-t slot — so no step-t slot is overwritten before all reads.
__device__ __forceinline__ unsigned long long gather_min(
    const unsigned long long* __restrict__ slotp, int t, unsigned long long* gmin_sh) {
    if (threadIdx.x < 64) {
        const unsigned want = (unsigned)t & 0xFFFu;
        unsigned long long k[SLOTS_PER_THREAD];
        for (;;) {
            #pragma unroll
            for (int s = 0; s < SLOTS_PER_THREAD; ++s)
                k[s] = __hip_atomic_load(&slotp[threadIdx.x + 64 * s],
                                         __ATOMIC_RELAXED, __HIP_MEMORY_SCOPE_AGENT);
            bool ok = true;
            #pragma unroll
            for (int s = 0; s < SLOTS_PER_THREAD; ++s)
                ok &= (((unsigned)(k[s] >> 20) & 0xFFFu) == want);
            if (ok) break;
        }
        unsigned long long lb = k[0];
        #pragma unroll
        for (int s = 1; s < SLOTS_PER_THREAD; ++s)
            if (k[s] < lb) lb = k[s];
        #pragma unroll
        for (int off = 32; off >= 1; off >>= 1) {
            unsigned long long o = shfl_down_u64(lb, off);
            lb = (o < lb) ? o : lb;
        }
        if (threadIdx.x == 0) *gmin_sh = lb;
    }
    __syncthreads();
    unsigned long long r = *gmin_sh;
    __syncthreads();
    return r;
}

// The entire round-4 step loop, templated on UNIT (= ell2 == 1.0f exactly).
// UNIT=true removes the three /ell2-family divides per point (division by 1.0f
// is an IEEE identity => bit-identical values); UNIT=false is byte-for-byte
// the verified round-4 path. Template (not runtime branch in the loop):
// the two instantiations never share register allocation at any program
// point — round-5 lesson, where an in-loop branch + restructure re-spilled.
template <bool UNIT>
__device__ __forceinline__ void run_steps(
    const float4* __restrict__ X4, const float4* __restrict__ S4,
    int* __restrict__ out, unsigned long long* __restrict__ slots,
    int m, int tid, int T, float ell2, float w, float dim_over_ell2,
    float4 (&xr0)[V], float4 (&xr1)[V],
    float (&ax2)[DIMS], float (&ax3)[DIMS],
    float (&as2)[DIMS], float (&as3)[(V - V3) * 4],
    float (&objr)[PPT], float (&lpr)[PPT],
    float4 (*s_ldsT)[2 * BLOCK], float4 (*s_lds3)[BLOCK],
    float4* xi4, float4* si4,
    unsigned long long* gmin_sh, unsigned long long* red_scratch)
{
    for (int t = 1; t < m; ++t) {
        const unsigned long long gmin =
            gather_min(slots + (size_t)((t - 1) & 1) * GRID, t - 1, gmin_sh);
        const int idx = (int)(gmin & 0xFFFFFull);
        if (blockIdx.x == 0 && threadIdx.x == 0) out[t - 1] = idx;

        // stage pivot row (x[idx], s[idx]) into LDS
        if (threadIdx.x < 16) {
            const size_t pb = (size_t)idx * V;
            if (threadIdx.x < 8) xi4[threadIdx.x] = X4[pb + threadIdx.x];
            else                 si4[threadIdx.x - 8] = S4[pb + (threadIdx.x - 8)];
        }
        __syncthreads();

        // outer-p / inner-v: FP summation order per accumulator is bit-identical
        // to the verified round-0/4 kernels.
        unsigned long long lbest = ~0ULL;
        #pragma unroll
        for (int p = 0; p < PPT; ++p) {
            float r2 = 0.0f, c1 = 0.0f, c2 = 0.0f, dss = 0.0f;
            #pragma unroll
            for (int v = 0; v < V; ++v) {
                const float4 xp = xi4[v];
                const float4 sp = si4[v];
                float4 xv, sv;
                if (p == 0)      { xv = xr0[v]; sv = s_ldsT[v][threadIdx.x]; }
                else if (p == 1) { xv = xr1[v]; sv = s_ldsT[v][BLOCK + threadIdx.x]; }
                else if (p == 2) {
                    xv.x = from_agpr(ax2[4 * v + 0]); xv.y = from_agpr(ax2[4 * v + 1]);
                    xv.z = from_agpr(ax2[4 * v + 2]); xv.w = from_agpr(ax2[4 * v + 3]);
                    sv.x = from_agpr(as2[4 * v + 0]); sv.y = from_agpr(as2[4 * v + 1]);
                    sv.z = from_agpr(as2[4 * v + 2]); sv.w = from_agpr(as2[4 * v + 3]);
                } else {
                    xv.x = from_agpr(ax3[4 * v + 0]); xv.y = from_agpr(ax3[4 * v + 1]);
                    xv.z = from_agpr(ax3[4 * v + 2]); xv.w = from_agpr(ax3[4 * v + 3]);
                    if (v < V3) sv = s_lds3[v][threadIdx.x];
                    else {
                        const int b = (v - V3) * 4;
                        sv.x = from_agpr(as3[b + 0]); sv.y = from_agpr(as3[b + 1]);
                        sv.z = from_agpr(as3[b + 2]); sv.w = from_agpr(as3[b + 3]);
                    }
                }
                float d;
                d = xp.x - xv.x; r2 += d * d; c1 += d * sp.x; c2 += sv.x * d; dss += sv.x * sp.x;
                d = xp.y - xv.y; r2 += d * d; c1 += d * sp.y; c2 += sv.y * d; dss += sv.y * sp.y;
                d = xp.z - xv.z; r2 += d * d; c1 += d * sp.z; c2 += sv.z * d; dss += sv.z * sp.z;
                d = xp.w - xv.w; r2 += d * d; c1 += d * sp.w; c2 += sv.w * d; dss += sv.w * sp.w;
            }
            float q, cross, tq;
            if constexpr (UNIT) {
                q = 1.0f + r2;                     // r2 / 1.0f == r2 exactly
                cross = (c1 - c2);
                tq = 3.0f * r2;
            } else {
                q = 1.0f + r2 / ell2;
                cross = (c1 - c2) / ell2;
                tq = 3.0f * r2 / (ell2 * ell2);
            }
            const float qi  = 1.0f / q;
            const float sq  = sqrtf(qi);        // q^-0.5
            const float g   = qi * sq;          // q^-1.5
            const float q25 = qi * qi * sq;     // q^-2.5
            const float k = ((dim_over_ell2 * g - tq * q25) + cross * g) + dss * sq;
            // +inf rows stay +inf (their loads were clamped to a real row => k finite)
            const float o = objr[p] + (2.0f * k - w * lpr[p]);
            objr[p] = o;
            const unsigned long long pk = pack_min(o, (unsigned)(tid + p * T));
            if (pk < lbest) lbest = pk;
        }
        post_slot(slots, block_min_reduce(lbest, red_scratch), t);
    }

    // -------- final argmin -> out[m-1] ----------------------------------------
    {
        const unsigned long long gmin =
            gather_min(slots + (size_t)((m - 1) & 1) * GRID, m - 1, gmin_sh);
        if (blockIdx.x == 0 && threadIdx.x == 0) out[m - 1] = (int)(gmin & 0xFFFFFull);
    }
}

// waves_per_eu(2,2): 2 waves/SIMD (the LDS cap enforces 1 block/CU anyway)
// => 256-register TOTAL budget per wave (arch + acc halves of the unified file).
__global__
__attribute__((amdgpu_flat_work_group_size(512, 512),
               amdgpu_waves_per_eu(2, 2)))
void stein_thin_persist(
    const float* __restrict__ x, const float* __restrict__ log_p,
    const float* __restrict__ score_p, const float* __restrict__ laplace,
    const float* __restrict__ ls_ptr, int* __restrict__ out,
    unsigned long long* __restrict__ slots, int N, int m)
{
    const int tid = blockIdx.x * BLOCK + threadIdx.x;
    const int T = GRID * BLOCK;          // 131072

    const float ell = ls_ptr[0];
    const float ell2 = ell * ell;
    const float w = 1.0f / (float)m;                 // weight_entropy = 1/m
    const float dim_over_ell2 = (float)DIMS / ell2;

    const float4* __restrict__ X4 = (const float4*)x;
    const float4* __restrict__ S4 = (const float4*)score_p;

    // LDS: tier A 128 KB + tier B 24 KB + pivot/reduce ~0.5 KB (conflict-free
    // transposed layout, SQ_LDS_BANK_CONFLICT = 0 verified).
    __shared__ float4 s_ldsT[V][2 * BLOCK];   // S-rows of points 0,1 (128 KB)
    __shared__ float4 s_lds3[V3][BLOCK];      // first 3 float4s of point 3 (24 KB)
    __shared__ float4 xi4[V];
    __shared__ float4 si4[V];
    __shared__ unsigned long long gmin_sh;
    __shared__ unsigned long long red_scratch[BLOCK / 64];

    // -------- persistent per-thread state ------------------------------------
    // arch VGPRs (<=128): xr0,xr1 (64) + objr/lpr (8) + workspace
    // AGPRs (116/128):    ax2,ax3 (x-rows of points 2,3) + as2 + as3 tail
    // LDS: S-rows of points 0,1 + first 3 float4s of point 3
    // => step loop has ZERO global data traffic and ZERO scratch traffic.
    float4 xr0[V];
    float4 xr1[V];
    float ax2[DIMS], ax3[DIMS];          // AGPR-resident (all indices constant)
    float as2[DIMS], as3[(V - V3) * 4];  // AGPR-resident
    float objr[PPT], lpr[PPT];

    {
        unsigned long long lbest = ~0ULL;
        #pragma unroll
        for (int p = 0; p < PPT; ++p) {
            const int j = tid + p * T;
            const bool act = (j < N);
            const int jc = act ? j : (N - 1);        // clamp: loads stay in-bounds
            const size_t base = (size_t)jc * V;
            float ss = 0.0f;
            #pragma unroll
            for (int v = 0; v < V; ++v) {
                const float4 s = S4[base + v];
                if (p < 2) s_ldsT[v][p * BLOCK + threadIdx.x] = s;
                if (p == 2) {
                    as2[4 * v + 0] = to_agpr(s.x); as2[4 * v + 1] = to_agpr(s.y);
                    as2[4 * v + 2] = to_agpr(s.z); as2[4 * v + 3] = to_agpr(s.w);
                }
                if (p == 3) {
                    if (v < V3) s_lds3[v][threadIdx.x] = s;
                    else {
                        const int b = (v - V3) * 4;
                        as3[b + 0] = to_agpr(s.x); as3[b + 1] = to_agpr(s.y);
                        as3[b + 2] = to_agpr(s.z); as3[b + 3] = to_agpr(s.w);
                    }
                }
                const float4 xx = X4[base + v];
                if (p == 0) xr0[v] = xx;
                else if (p == 1) xr1[v] = xx;
                else if (p == 2) {
                    ax2[4 * v + 0] = to_agpr(xx.x); ax2[4 * v + 1] = to_agpr(xx.y);
                    ax2[4 * v + 2] = to_agpr(xx.z); ax2[4 * v + 3] = to_agpr(xx.w);
                } else {
                    ax3[4 * v + 0] = to_agpr(xx.x); ax3[4 * v + 1] = to_agpr(xx.y);
                    ax3[4 * v + 2] = to_agpr(xx.z); ax3[4 * v + 3] = to_agpr(xx.w);
                }
                ss += s.x * s.x; ss += s.y * s.y; ss += s.z * s.z; ss += s.w * s.w;
            }
            lpr[p] = log_p[jc];
            // identical source shape to the previously verified kernels:
            float o = ((dim_over_ell2 + ss) + laplace[jc]) - w * log_p[jc];
            if (!act) o = __int_as_float(0x7F800000);   // +inf: never selected
            objr[p] = o;
            const unsigned long long pk = pack_min(o, (unsigned)j);
            if (pk < lbest) lbest = pk;
        }
        post_slot(slots, block_min_reduce(lbest, red_scratch), 0);
    }
    __syncthreads();   // LDS tiers fully populated before the step loop

    // -------- steps 1..m-1 (template-split on unit lengthscale) ---------------
    if (ell2 == 1.0f) {
        run_steps<true>(X4, S4, out, slots, m, tid, T, ell2, w, dim_over_ell2,
                        xr0, xr1, ax2, ax3, as2, as3, objr, lpr,
                        s_ldsT, s_lds3, xi4, si4, &gmin_sh, red_scratch);
    } else {
        run_steps<false>(X4, S4, out, slots, m, tid, T, ell2, w, dim_over_ell2,
                         xr0, xr1, ax2, ax3, as2, as3, objr, lpr,
                         s_ldsT, s_lds3, xi4, si4, &gmin_sh, red_scratch);
    }
}

extern "C" void kernel_launch(void* const* d_in, const int* in_sizes, int n_in,
                              void* d_out, int out_size, void* d_ws, size_t ws_size,
                              hipStream_t stream) {
    const float* x        = (const float*)d_in[0];
    const float* log_p    = (const float*)d_in[1];
    const float* score_p  = (const float*)d_in[2];
    const float* laplace  = (const float*)d_in[3];
    const float* ls_ptr   = (const float*)d_in[4];

    int* out = (int*)d_out;
    int N = in_sizes[1];            // log_p has N elements
    int m = out_size;

    unsigned long long* slots = (unsigned long long*)d_ws;  // 2*GRID u64 = 4 KB

    // Single deterministic path: plain launch, identical on every call
    // (correctness call, graph capture, tripwire). 152 KB LDS => exactly
    // 1 block/CU => 256 blocks on 256 CUs are structurally co-resident.
    stein_thin_persist<<<dim3(GRID), dim3(BLOCK), 0, stream>>>(
        x, log_p, score_p, laplace, ls_ptr, out, slots, N, m);
}

// Round 7
// 11775.805 us; speedup vs baseline: 5.7484x; 1.6363x over previous
//
#include <hip/hip_runtime.h>

#define BLOCK 512
#define GRID  256          // = #CUs; 152KB LDS => 1 block/CU => plain launch co-resident
#define PPT   4            // GRID*BLOCK*PPT = 524288 >= N
#define V     8            // DIMS/4 float4s per row
#define V3    3            // float4s of point 3 parked in LDS (rest in AGPRs)
#define DIMS  32
#define SLOTS_PER_THREAD (GRID / 64)   // wave-0 gather: 4 slots per lane

// ---- explicit AGPR residency (round-4 win: FETCH 30.4GB -> 1.9GB) -----------
// The allocator splits the unified file 128 arch + 128 acc and spills overflow
// ARRAYS to memory scratch instead of the idle AGPR half. These helpers pin
// values into AGPRs. volatile: LICM must not hoist the reads back out of the
// step loop (that would re-inflate arch pressure and re-spill).
// Rounds 5/6 lesson: the step loop is at a regalloc knife's edge — NO wrapper
// functions, NO templates, NO in-loop uniform branches around it.
__device__ __forceinline__ float to_agpr(float v) {
    float r;
    asm volatile("v_accvgpr_write_b32 %0, %1" : "=a"(r) : "v"(v));
    return r;
}
__device__ __forceinline__ float from_agpr(float a) {
    float r;
    asm volatile("v_accvgpr_read_b32 %0, %1" : "=v"(r) : "a"(a));
    return r;
}

// Monotone map: smaller float -> smaller u32 key (ties broken by index).
__device__ __forceinline__ unsigned pack_f32(float v) {
    unsigned u = __float_as_uint(v);
    return (u & 0x80000000u) ? ~u : (u | 0x80000000u);
}

__device__ __forceinline__ unsigned long long pack_min(float v, unsigned idx) {
    return ((unsigned long long)pack_f32(v) << 32) | (unsigned long long)idx;
}

__device__ __forceinline__ unsigned long long shfl_down_u64(unsigned long long v, int off) {
    unsigned lo = (unsigned)(v & 0xffffffffu);
    unsigned hi = (unsigned)(v >> 32);
    lo = __shfl_down(lo, off, 64);
    hi = __shfl_down(hi, off, 64);
    return ((unsigned long long)hi << 32) | (unsigned long long)lo;
}

// Butterfly: ALL 64 lanes end with the wave-wide min.
__device__ __forceinline__ unsigned long long shfl_xor_u64(unsigned long long v, int mask) {
    unsigned lo = (unsigned)(v & 0xffffffffu);
    unsigned hi = (unsigned)(v >> 32);
    lo = __shfl_xor(lo, mask, 64);
    hi = __shfl_xor(hi, mask, 64);
    return ((unsigned long long)hi << 32) | (unsigned long long)lo;
}

// Full-block min reduction (init phase only); every thread returns the block min.
__device__ __forceinline__ unsigned long long block_min_reduce(unsigned long long v,
                                                              unsigned long long* scratch) {
    #pragma unroll
    for (int off = 32; off >= 1; off >>= 1) {
        unsigned long long o = shfl_down_u64(v, off);
        v = (o < v) ? o : v;
    }
    const int wave = threadIdx.x >> 6;
    const int lane = threadIdx.x & 63;
    if (lane == 0) scratch[wave] = v;
    __syncthreads();
    unsigned long long r = scratch[0];
    #pragma unroll
    for (int i = 1; i < (BLOCK / 64); ++i) {
        unsigned long long o = scratch[i];
        r = (o < r) ? o : r;
    }
    __syncthreads();  // scratch safe for reuse
    return r;
}

// Post this block's min for step t. Slot key: [val:32 | step:12 | idx:20].
__device__ __forceinline__ void post_slot(unsigned long long* __restrict__ slots,
                                          unsigned long long blockmin, int t) {
    if (threadIdx.x == 0) {
        const unsigned long long val = blockmin >> 32;
        const unsigned long long idx = blockmin & 0xFFFFFull;   // all idx < 2^20
        const unsigned long long key =
            (val << 32) | ((unsigned long long)((unsigned)t & 0xFFFu) << 20) | idx;
        __hip_atomic_store(&slots[(size_t)(t & 1) * GRID + blockIdx.x], key,
                           __ATOMIC_RELAXED, __HIP_MEMORY_SCOPE_AGENT);
    }
}

// Fused gather + pivot stage: wave0 polls all GRID slots for step t, butterfly
// gives the grid min to all 64 lanes, lanes<16 immediately prefetch the pivot
// row (HBM latency overlaps the other waves arriving at the barrier), lane 0
// publishes gmin. ONE barrier releases the block.
// Hazard audit (all buffers): thread0's scratch-read + post(t) happens-before
// any block's poll(t) success, which happens-before wave0's arrival here at
// t+1, which happens-before the next xi4/si4/gmin_sh writes — so no reader of
// step-t state can race the t+1 writers. The 2-buffer slot parity reuse is as
// in rounds 0-4: a block posts t+2 only after gathering all t+1 posts, whose
// authors had finished reading every step-t slot.
__device__ __forceinline__ void gather_stage(
    const unsigned long long* __restrict__ slotp, int t,
    unsigned long long* gmin_sh,
    const float4* __restrict__ X4, const float4* __restrict__ S4,
    float4* xi4, float4* si4)
{
    if (threadIdx.x < 64) {
        const unsigned want = (unsigned)t & 0xFFFu;
        unsigned long long k[SLOTS_PER_THREAD];
        for (;;) {
            #pragma unroll
            for (int s = 0; s < SLOTS_PER_THREAD; ++s)
                k[s] = __hip_atomic_load(&slotp[threadIdx.x + 64 * s],
                                         __ATOMIC_RELAXED, __HIP_MEMORY_SCOPE_AGENT);
            bool ok = true;
            #pragma unroll
            for (int s = 0; s < SLOTS_PER_THREAD; ++s)
                ok &= (((unsigned)(k[s] >> 20) & 0xFFFu) == want);
            if (ok) break;
        }
        unsigned long long lb = k[0];
        #pragma unroll
        for (int s = 1; s < SLOTS_PER_THREAD; ++s)
            if (k[s] < lb) lb = k[s];
        #pragma unroll
        for (int mask = 32; mask >= 1; mask >>= 1) {
            unsigned long long o = shfl_xor_u64(lb, mask);
            lb = (o < lb) ? o : lb;
        }
        const int idx = (int)(lb & 0xFFFFFull);
        if (threadIdx.x < 16) {
            const size_t pb = (size_t)idx * V;
            if (threadIdx.x < 8) xi4[threadIdx.x] = X4[pb + threadIdx.x];
            else                 si4[threadIdx.x - 8] = S4[pb + (threadIdx.x - 8)];
        }
        if (threadIdx.x == 0) *gmin_sh = lb;
    }
    __syncthreads();
}

// waves_per_eu(2,2): 2 waves/SIMD (the LDS cap enforces 1 block/CU anyway)
// => 256-register TOTAL budget per wave (arch + acc halves of the unified file).
__global__
__attribute__((amdgpu_flat_work_group_size(512, 512),
               amdgpu_waves_per_eu(2, 2)))
void stein_thin_persist(
    const float* __restrict__ x, const float* __restrict__ log_p,
    const float* __restrict__ score_p, const float* __restrict__ laplace,
    const float* __restrict__ ls_ptr, int* __restrict__ out,
    unsigned long long* __restrict__ slots, int N, int m)
{
    const int tid = blockIdx.x * BLOCK + threadIdx.x;
    const int T = GRID * BLOCK;          // 131072
    const int lane = threadIdx.x & 63;
    const int wave = threadIdx.x >> 6;

    const float ell = ls_ptr[0];
    const float ell2 = ell * ell;
    const float w = 1.0f / (float)m;                 // weight_entropy = 1/m
    const float dim_over_ell2 = (float)DIMS / ell2;
    // Divide->multiply: for the unit lengthscale (ell2 == 1.0f) inv_ell2 == 1.0f
    // and x*1.0f == x/1.0f bit-exactly, so the step math is identical to the
    // verified round-4 kernel on the bench data. Fewer temporaries than the
    // v_div_scale/fmas/fixup sequences => register pressure strictly decreases.
    const float inv_ell2 = 1.0f / ell2;
    const float inv2 = inv_ell2 * inv_ell2;

    const float4* __restrict__ X4 = (const float4*)x;
    const float4* __restrict__ S4 = (const float4*)score_p;

    // LDS: tier A 128 KB + tier B 24 KB + pivot/reduce ~0.5 KB (conflict-free
    // transposed layout, SQ_LDS_BANK_CONFLICT = 0 verified).
    __shared__ float4 s_ldsT[V][2 * BLOCK];   // S-rows of points 0,1 (128 KB)
    __shared__ float4 s_lds3[V3][BLOCK];      // first 3 float4s of point 3 (24 KB)
    __shared__ float4 xi4[V];
    __shared__ float4 si4[V];
    __shared__ unsigned long long gmin_sh;
    __shared__ unsigned long long red_scratch[BLOCK / 64];

    // -------- persistent per-thread state ------------------------------------
    // arch VGPRs (<=128): xr0,xr1 (64) + objr/lpr (8) + workspace
    // AGPRs (116/128):    ax2,ax3 (x-rows of points 2,3) + as2 + as3 tail
    // LDS: S-rows of points 0,1 + first 3 float4s of point 3
    // => step loop has ZERO global data traffic and ZERO scratch traffic.
    float4 xr0[V];
    float4 xr1[V];
    float ax2[DIMS], ax3[DIMS];          // AGPR-resident (all indices constant)
    float as2[DIMS], as3[(V - V3) * 4];  // AGPR-resident
    float objr[PPT], lpr[PPT];

    {
        unsigned long long lbest = ~0ULL;
        #pragma unroll
        for (int p = 0; p < PPT; ++p) {
            const int j = tid + p * T;
            const bool act = (j < N);
            const int jc = act ? j : (N - 1);        // clamp: loads stay in-bounds
            const size_t base = (size_t)jc * V;
            float ss = 0.0f;
            #pragma unroll
            for (int v = 0; v < V; ++v) {
                const float4 s = S4[base + v];
                if (p < 2) s_ldsT[v][p * BLOCK + threadIdx.x] = s;
                if (p == 2) {
                    as2[4 * v + 0] = to_agpr(s.x); as2[4 * v + 1] = to_agpr(s.y);
                    as2[4 * v + 2] = to_agpr(s.z); as2[4 * v + 3] = to_agpr(s.w);
                }
                if (p == 3) {
                    if (v < V3) s_lds3[v][threadIdx.x] = s;
                    else {
                        const int b = (v - V3) * 4;
                        as3[b + 0] = to_agpr(s.x); as3[b + 1] = to_agpr(s.y);
                        as3[b + 2] = to_agpr(s.z); as3[b + 3] = to_agpr(s.w);
                    }
                }
                const float4 xx = X4[base + v];
                if (p == 0) xr0[v] = xx;
                else if (p == 1) xr1[v] = xx;
                else if (p == 2) {
                    ax2[4 * v + 0] = to_agpr(xx.x); ax2[4 * v + 1] = to_agpr(xx.y);
                    ax2[4 * v + 2] = to_agpr(xx.z); ax2[4 * v + 3] = to_agpr(xx.w);
                } else {
                    ax3[4 * v + 0] = to_agpr(xx.x); ax3[4 * v + 1] = to_agpr(xx.y);
                    ax3[4 * v + 2] = to_agpr(xx.z); ax3[4 * v + 3] = to_agpr(xx.w);
                }
                ss += s.x * s.x; ss += s.y * s.y; ss += s.z * s.z; ss += s.w * s.w;
            }
            lpr[p] = log_p[jc];
            // identical source shape to the previously verified kernels:
            float o = ((dim_over_ell2 + ss) + laplace[jc]) - w * log_p[jc];
            if (!act) o = __int_as_float(0x7F800000);   // +inf: never selected
            objr[p] = o;
            const unsigned long long pk = pack_min(o, (unsigned)j);
            if (pk < lbest) lbest = pk;
        }
        post_slot(slots, block_min_reduce(lbest, red_scratch), 0);
    }
    __syncthreads();   // LDS tiers fully populated before the step loop

    // -------- steps 1..m-1: 3 barriers per step ------------------------------
    // gather_stage (1 barrier) -> compute -> lane0s->scratch (1 barrier) ->
    // thread0 block-min + post. Hazard audit in gather_stage's comment.
    for (int t = 1; t < m; ++t) {
        gather_stage(slots + (size_t)((t - 1) & 1) * GRID, t - 1, &gmin_sh,
                     X4, S4, xi4, si4);
        if (blockIdx.x == 0 && threadIdx.x == 0)
            out[t - 1] = (int)(gmin_sh & 0xFFFFFull);

        // outer-p / inner-v: FP summation order per accumulator is bit-identical
        // to the verified round-0/4 kernels.
        unsigned long long lbest = ~0ULL;
        #pragma unroll
        for (int p = 0; p < PPT; ++p) {
            float r2 = 0.0f, c1 = 0.0f, c2 = 0.0f, dss = 0.0f;
            #pragma unroll
            for (int v = 0; v < V; ++v) {
                const float4 xp = xi4[v];
                const float4 sp = si4[v];
                float4 xv, sv;
                if (p == 0)      { xv = xr0[v]; sv = s_ldsT[v][threadIdx.x]; }
                else if (p == 1) { xv = xr1[v]; sv = s_ldsT[v][BLOCK + threadIdx.x]; }
                else if (p == 2) {
                    xv.x = from_agpr(ax2[4 * v + 0]); xv.y = from_agpr(ax2[4 * v + 1]);
                    xv.z = from_agpr(ax2[4 * v + 2]); xv.w = from_agpr(ax2[4 * v + 3]);
                    sv.x = from_agpr(as2[4 * v + 0]); sv.y = from_agpr(as2[4 * v + 1]);
                    sv.z = from_agpr(as2[4 * v + 2]); sv.w = from_agpr(as2[4 * v + 3]);
                } else {
                    xv.x = from_agpr(ax3[4 * v + 0]); xv.y = from_agpr(ax3[4 * v + 1]);
                    xv.z = from_agpr(ax3[4 * v + 2]); xv.w = from_agpr(ax3[4 * v + 3]);
                    if (v < V3) sv = s_lds3[v][threadIdx.x];
                    else {
                        const int b = (v - V3) * 4;
                        sv.x = from_agpr(as3[b + 0]); sv.y = from_agpr(as3[b + 1]);
                        sv.z = from_agpr(as3[b + 2]); sv.w = from_agpr(as3[b + 3]);
                    }
                }
                float d;
                d = xp.x - xv.x; r2 += d * d; c1 += d * sp.x; c2 += sv.x * d; dss += sv.x * sp.x;
                d = xp.y - xv.y; r2 += d * d; c1 += d * sp.y; c2 += sv.y * d; dss += sv.y * sp.y;
                d = xp.z - xv.z; r2 += d * d; c1 += d * sp.z; c2 += sv.z * d; dss += sv.z * sp.z;
                d = xp.w - xv.w; r2 += d * d; c1 += d * sp.w; c2 += sv.w * d; dss += sv.w * sp.w;
            }
            const float q   = 1.0f + r2 * inv_ell2;
            const float qi  = 1.0f / q;
            const float sq  = sqrtf(qi);        // q^-0.5
            const float g   = qi * sq;          // q^-1.5
            const float q25 = qi * qi * sq;     // q^-2.5
            const float cross = (c1 - c2) * inv_ell2;
            const float k = ((dim_over_ell2 * g - 3.0f * r2 * inv2 * q25)
                             + cross * g) + dss * sq;
            // +inf rows stay +inf (their loads were clamped to a real row => k finite)
            const float o = objr[p] + (2.0f * k - w * lpr[p]);
            objr[p] = o;
            const unsigned long long pk = pack_min(o, (unsigned)(tid + p * T));
            if (pk < lbest) lbest = pk;
        }

        #pragma unroll
        for (int off = 32; off >= 1; off >>= 1) {
            unsigned long long o = shfl_down_u64(lbest, off);
            lbest = (o < lbest) ? o : lbest;
        }
        if (lane == 0) red_scratch[wave] = lbest;
        __syncthreads();
        if (threadIdx.x == 0) {
            unsigned long long r = red_scratch[0];
            #pragma unroll
            for (int i = 1; i < (BLOCK / 64); ++i) {
                unsigned long long o = red_scratch[i];
                r = (o < r) ? o : r;
            }
            post_slot(slots, r, t);
        }
    }

    // -------- final argmin -> out[m-1] ----------------------------------------
    {
        gather_stage(slots + (size_t)((m - 1) & 1) * GRID, m - 1, &gmin_sh,
                     X4, S4, xi4, si4);
        if (blockIdx.x == 0 && threadIdx.x == 0)
            out[m - 1] = (int)(gmin_sh & 0xFFFFFull);
    }
}

extern "C" void kernel_launch(void* const* d_in, const int* in_sizes, int n_in,
                              void* d_out, int out_size, void* d_ws, size_t ws_size,
                              hipStream_t stream) {
    const float* x        = (const float*)d_in[0];
    const float* log_p    = (const float*)d_in[1];
    const float* score_p  = (const float*)d_in[2];
    const float* laplace  = (const float*)d_in[3];
    const float* ls_ptr   = (const float*)d_in[4];

    int* out = (int*)d_out;
    int N = in_sizes[1];            // log_p has N elements
    int m = out_size;

    unsigned long long* slots = (unsigned long long*)d_ws;  // 2*GRID u64 = 4 KB

    // Single deterministic path: plain launch, identical on every call
    // (correctness call, graph capture, tripwire). 152 KB LDS => exactly
    // 1 block/CU => 256 blocks on 256 CUs are structurally co-resident.
    stein_thin_persist<<<dim3(GRID), dim3(BLOCK), 0, stream>>>(
        x, log_p, score_p, laplace, ls_ptr, out, slots, N, m);
}

// Round 9
// 7065.443 us; speedup vs baseline: 9.5807x; 1.6667x over previous
//
#include <hip/hip_runtime.h>

#define BLOCK 512
#define GRID  256          // = #CUs; 152KB LDS => 1 block/CU => plain launch co-resident
#define PPT   4            // GRID*BLOCK*PPT = 524288 >= N
#define V     8            // DIMS/4 float4s per row
#define V3    3            // float4s of point 3 parked in LDS (rest in AGPRs)
#define DIMS  32
#define SLOTS_PER_THREAD (GRID / 64)   // wave-0 gather: 4 slots per lane

// ---- explicit AGPR residency (round-4 win: FETCH 30.4GB -> 1.9GB) -----------
// The allocator splits the unified file 128 arch + 128 acc and spills overflow
// ARRAYS to memory scratch instead of the idle AGPR half. These helpers pin
// values into AGPRs. volatile: LICM must not hoist the reads back out of the
// step loop (that would re-inflate arch pressure and re-spill).
// Rounds 5/6 lesson: the step loop is at a regalloc knife's edge — NO wrapper
// functions, NO templates, NO in-loop uniform branches.
// Round 8 lesson: NEVER issue a load whose result is unconsumed — a dead asm
// load dest is reused by regalloc and the async retire clobbers live registers.
__device__ __forceinline__ float to_agpr(float v) {
    float r;
    asm volatile("v_accvgpr_write_b32 %0, %1" : "=a"(r) : "v"(v));
    return r;
}
__device__ __forceinline__ float from_agpr(float a) {
    float r;
    asm volatile("v_accvgpr_read_b32 %0, %1" : "=v"(r) : "a"(a));
    return r;
}

// Monotone map: smaller float -> smaller u32 key (ties broken by index).
__device__ __forceinline__ unsigned pack_f32(float v) {
    unsigned u = __float_as_uint(v);
    return (u & 0x80000000u) ? ~u : (u | 0x80000000u);
}

__device__ __forceinline__ unsigned long long pack_min(float v, unsigned idx) {
    return ((unsigned long long)pack_f32(v) << 32) | (unsigned long long)idx;
}

__device__ __forceinline__ unsigned long long shfl_down_u64(unsigned long long v, int off) {
    unsigned lo = (unsigned)(v & 0xffffffffu);
    unsigned hi = (unsigned)(v >> 32);
    lo = __shfl_down(lo, off, 64);
    hi = __shfl_down(hi, off, 64);
    return ((unsigned long long)hi << 32) | (unsigned long long)lo;
}

// Butterfly: ALL 64 lanes end with the wave-wide min.
__device__ __forceinline__ unsigned long long shfl_xor_u64(unsigned long long v, int mask) {
    unsigned lo = (unsigned)(v & 0xffffffffu);
    unsigned hi = (unsigned)(v >> 32);
    lo = __shfl_xor(lo, mask, 64);
    hi = __shfl_xor(hi, mask, 64);
    return ((unsigned long long)hi << 32) | (unsigned long long)lo;
}

// Full-block min reduction (init phase only); every thread returns the block min.
__device__ __forceinline__ unsigned long long block_min_reduce(unsigned long long v,
                                                              unsigned long long* scratch) {
    #pragma unroll
    for (int off = 32; off >= 1; off >>= 1) {
        unsigned long long o = shfl_down_u64(v, off);
        v = (o < v) ? o : v;
    }
    const int wave = threadIdx.x >> 6;
    const int lane = threadIdx.x & 63;
    if (lane == 0) scratch[wave] = v;
    __syncthreads();
    unsigned long long r = scratch[0];
    #pragma unroll
    for (int i = 1; i < (BLOCK / 64); ++i) {
        unsigned long long o = scratch[i];
        r = (o < r) ? o : r;
    }
    __syncthreads();  // scratch safe for reuse
    return r;
}

// Post this block's min for step t. Slot key: [val:32 | step:12 | idx:20].
__device__ __forceinline__ void post_slot(unsigned long long* __restrict__ slots,
                                          unsigned long long blockmin, int t) {
    if (threadIdx.x == 0) {
        const unsigned long long val = blockmin >> 32;
        const unsigned long long idx = blockmin & 0xFFFFFull;   // all idx < 2^20
        const unsigned long long key =
            (val << 32) | ((unsigned long long)((unsigned)t & 0xFFFu) << 20) | idx;
        __hip_atomic_store(&slots[(size_t)(t & 1) * GRID + blockIdx.x], key,
                           __ATOMIC_RELAXED, __HIP_MEMORY_SCOPE_AGENT);
    }
}

// Fused gather + pivot stage: wave0 polls all GRID slots for step t, butterfly
// gives the grid min to all 64 lanes, lanes<16 immediately fetch the pivot row
// (L3-warm: x/score_p fit in the 256MB IF since init), lane 0 publishes gmin.
// ONE barrier releases the block.
// Hazard audit (all buffers): thread0's scratch-read + post(t) happens-before
// any block's poll(t) success, which happens-before wave0's arrival here at
// t+1, which happens-before the next xi4/si4/gmin_sh writes — so no reader of
// step-t state can race the t+1 writers. The 2-buffer slot parity reuse is as
// in rounds 0-4: a block posts t+2 only after gathering all t+1 posts, whose
// authors had finished reading every step-t slot.
__device__ __forceinline__ void gather_stage(
    const unsigned long long* __restrict__ slotp, int t,
    unsigned long long* gmin_sh,
    const float4* __restrict__ X4, const float4* __restrict__ S4,
    float4* xi4, float4* si4)
{
    if (threadIdx.x < 64) {
        const unsigned want = (unsigned)t & 0xFFFu;
        unsigned long long k[SLOTS_PER_THREAD];
        for (;;) {
            #pragma unroll
            for (int s = 0; s < SLOTS_PER_THREAD; ++s)
                k[s] = __hip_atomic_load(&slotp[threadIdx.x + 64 * s],
                                         __ATOMIC_RELAXED, __HIP_MEMORY_SCOPE_AGENT);
            bool ok = true;
            #pragma unroll
            for (int s = 0; s < SLOTS_PER_THREAD; ++s)
                ok &= (((unsigned)(k[s] >> 20) & 0xFFFu) == want);
            if (ok) break;
        }
        unsigned long long lb = k[0];
        #pragma unroll
        for (int s = 1; s < SLOTS_PER_THREAD; ++s)
            if (k[s] < lb) lb = k[s];
        #pragma unroll
        for (int mask = 32; mask >= 1; mask >>= 1) {
            unsigned long long o = shfl_xor_u64(lb, mask);
            lb = (o < lb) ? o : lb;
        }
        const int idx = (int)(lb & 0xFFFFFull);
        if (threadIdx.x < 16) {
            const size_t pb = (size_t)idx * V;
            if (threadIdx.x < 8) xi4[threadIdx.x] = X4[pb + threadIdx.x];
            else                 si4[threadIdx.x - 8] = S4[pb + (threadIdx.x - 8)];
        }
        if (threadIdx.x == 0) *gmin_sh = lb;
    }
    __syncthreads();
}

// waves_per_eu(2,2): 2 waves/SIMD (the LDS cap enforces 1 block/CU anyway)
// => 256-register TOTAL budget per wave (arch + acc halves of the unified file).
__global__
__attribute__((amdgpu_flat_work_group_size(512, 512),
               amdgpu_waves_per_eu(2, 2)))
void stein_thin_persist(
    const float* __restrict__ x, const float* __restrict__ log_p,
    const float* __restrict__ score_p, const float* __restrict__ laplace,
    const float* __restrict__ ls_ptr, int* __restrict__ out,
    unsigned long long* __restrict__ slots, int N, int m)
{
    const int tid = blockIdx.x * BLOCK + threadIdx.x;
    const int T = GRID * BLOCK;          // 131072
    const int lane = threadIdx.x & 63;
    const int wave = threadIdx.x >> 6;

    const float ell = ls_ptr[0];
    const float ell2 = ell * ell;
    const float w = 1.0f / (float)m;                 // weight_entropy = 1/m
    const float dim_over_ell2 = (float)DIMS / ell2;
    // Divide->multiply: for the unit lengthscale (ell2 == 1.0f) inv_ell2 == 1.0f
    // and x*1.0f == x/1.0f bit-exactly (round-7 verified).
    const float inv_ell2 = 1.0f / ell2;
    const float inv2 = inv_ell2 * inv_ell2;

    const float4* __restrict__ X4 = (const float4*)x;
    const float4* __restrict__ S4 = (const float4*)score_p;

    // LDS: tier A 128 KB + tier B 24 KB + pivot/reduce ~0.5 KB (conflict-free
    // transposed layout, SQ_LDS_BANK_CONFLICT = 0 verified).
    __shared__ float4 s_ldsT[V][2 * BLOCK];   // S-rows of points 0,1 (128 KB)
    __shared__ float4 s_lds3[V3][BLOCK];      // first 3 float4s of point 3 (24 KB)
    __shared__ float4 xi4[V];
    __shared__ float4 si4[V];
    __shared__ unsigned long long gmin_sh;
    __shared__ unsigned long long red_scratch[BLOCK / 64];

    // -------- persistent per-thread state ------------------------------------
    // arch VGPRs (<=128): xr0,xr1 (64) + acc (16) + objr/lpr (8) + workspace
    // AGPRs (116/128):    ax2,ax3 (x-rows of points 2,3) + as2 + as3 tail
    // LDS: S-rows of points 0,1 + first 3 float4s of point 3
    // => step loop has ZERO global data traffic and ZERO scratch traffic.
    float4 xr0[V];
    float4 xr1[V];
    float ax2[DIMS], ax3[DIMS];          // AGPR-resident (all indices constant)
    float as2[DIMS], as3[(V - V3) * 4];  // AGPR-resident
    float objr[PPT], lpr[PPT];

    {
        unsigned long long lbest = ~0ULL;
        #pragma unroll
        for (int p = 0; p < PPT; ++p) {
            const int j = tid + p * T;
            const bool act = (j < N);
            const int jc = act ? j : (N - 1);        // clamp: loads stay in-bounds
            const size_t base = (size_t)jc * V;
            float ss = 0.0f;
            #pragma unroll
            for (int v = 0; v < V; ++v) {
                const float4 s = S4[base + v];
                if (p < 2) s_ldsT[v][p * BLOCK + threadIdx.x] = s;
                if (p == 2) {
                    as2[4 * v + 0] = to_agpr(s.x); as2[4 * v + 1] = to_agpr(s.y);
                    as2[4 * v + 2] = to_agpr(s.z); as2[4 * v + 3] = to_agpr(s.w);
                }
                if (p == 3) {
                    if (v < V3) s_lds3[v][threadIdx.x] = s;
                    else {
                        const int b = (v - V3) * 4;
                        as3[b + 0] = to_agpr(s.x); as3[b + 1] = to_agpr(s.y);
                        as3[b + 2] = to_agpr(s.z); as3[b + 3] = to_agpr(s.w);
                    }
                }
                const float4 xx = X4[base + v];
                if (p == 0) xr0[v] = xx;
                else if (p == 1) xr1[v] = xx;
                else if (p == 2) {
                    ax2[4 * v + 0] = to_agpr(xx.x); ax2[4 * v + 1] = to_agpr(xx.y);
                    ax2[4 * v + 2] = to_agpr(xx.z); ax2[4 * v + 3] = to_agpr(xx.w);
                } else {
                    ax3[4 * v + 0] = to_agpr(xx.x); ax3[4 * v + 1] = to_agpr(xx.y);
                    ax3[4 * v + 2] = to_agpr(xx.z); ax3[4 * v + 3] = to_agpr(xx.w);
                }
                ss += s.x * s.x; ss += s.y * s.y; ss += s.z * s.z; ss += s.w * s.w;
            }
            lpr[p] = log_p[jc];
            // identical source shape to the previously verified kernels:
            float o = ((dim_over_ell2 + ss) + laplace[jc]) - w * log_p[jc];
            if (!act) o = __int_as_float(0x7F800000);   // +inf: never selected
            objr[p] = o;
            const unsigned long long pk = pack_min(o, (unsigned)j);
            if (pk < lbest) lbest = pk;
        }
        post_slot(slots, block_min_reduce(lbest, red_scratch), 0);
    }
    __syncthreads();   // LDS tiers fully populated before the step loop

    // -------- steps 1..m-1: 3 barriers per step ------------------------------
    // gather_stage (1 barrier) -> compute -> lane0s->scratch (1 barrier) ->
    // thread0 block-min + post. Hazard audit in gather_stage's comment.
    for (int t = 1; t < m; ++t) {
        gather_stage(slots + (size_t)((t - 1) & 1) * GRID, t - 1, &gmin_sh,
                     X4, S4, xi4, si4);
        if (blockIdx.x == 0 && threadIdx.x == 0)
            out[t - 1] = (int)(gmin_sh & 0xFFFFFull);

        // OUTER-v / INNER-p (round-9 change): pivot xi4[v]/si4[v] read ONCE per
        // v instead of once per (p,v) — removes 48 broadcast ds_read_b128 per
        // thread per step from the shared per-CU LDS pipe (8 waves x ~2.8us of
        // pipe occupancy was a hidden serial term). Per-accumulator FP order
        // (v ascending, x/y/z/w) is unchanged => bit-identical results.
        // 16 accumulators, all compile-time-indexed (SROA -> registers).
        float r2a[PPT], c1a[PPT], c2a[PPT], dssa[PPT];
        #pragma unroll
        for (int p = 0; p < PPT; ++p) {
            r2a[p] = 0.0f; c1a[p] = 0.0f; c2a[p] = 0.0f; dssa[p] = 0.0f;
        }

        #pragma unroll
        for (int v = 0; v < V; ++v) {
            const float4 xp = xi4[v];
            const float4 sp = si4[v];
            #pragma unroll
            for (int p = 0; p < PPT; ++p) {
                float4 xv, sv;
                if (p == 0)      { xv = xr0[v]; sv = s_ldsT[v][threadIdx.x]; }
                else if (p == 1) { xv = xr1[v]; sv = s_ldsT[v][BLOCK + threadIdx.x]; }
                else if (p == 2) {
                    xv.x = from_agpr(ax2[4 * v + 0]); xv.y = from_agpr(ax2[4 * v + 1]);
                    xv.z = from_agpr(ax2[4 * v + 2]); xv.w = from_agpr(ax2[4 * v + 3]);
                    sv.x = from_agpr(as2[4 * v + 0]); sv.y = from_agpr(as2[4 * v + 1]);
                    sv.z = from_agpr(as2[4 * v + 2]); sv.w = from_agpr(as2[4 * v + 3]);
                } else {
                    xv.x = from_agpr(ax3[4 * v + 0]); xv.y = from_agpr(ax3[4 * v + 1]);
                    xv.z = from_agpr(ax3[4 * v + 2]); xv.w = from_agpr(ax3[4 * v + 3]);
                    if (v < V3) sv = s_lds3[v][threadIdx.x];
                    else {
                        const int b = (v - V3) * 4;
                        sv.x = from_agpr(as3[b + 0]); sv.y = from_agpr(as3[b + 1]);
                        sv.z = from_agpr(as3[b + 2]); sv.w = from_agpr(as3[b + 3]);
                    }
                }
                float d;
                d = xp.x - xv.x; r2a[p] += d * d; c1a[p] += d * sp.x; c2a[p] += sv.x * d; dssa[p] += sv.x * sp.x;
                d = xp.y - xv.y; r2a[p] += d * d; c1a[p] += d * sp.y; c2a[p] += sv.y * d; dssa[p] += sv.y * sp.y;
                d = xp.z - xv.z; r2a[p] += d * d; c1a[p] += d * sp.z; c2a[p] += sv.z * d; dssa[p] += sv.z * sp.z;
                d = xp.w - xv.w; r2a[p] += d * d; c1a[p] += d * sp.w; c2a[p] += sv.w * d; dssa[p] += sv.w * sp.w;
            }
        }

        unsigned long long lbest = ~0ULL;
        #pragma unroll
        for (int p = 0; p < PPT; ++p) {
            const float r2 = r2a[p];
            const float q   = 1.0f + r2 * inv_ell2;
            const float qi  = 1.0f / q;
            const float sq  = sqrtf(qi);        // q^-0.5
            const float g   = qi * sq;          // q^-1.5
            const float q25 = qi * qi * sq;     // q^-2.5
            const float cross = (c1a[p] - c2a[p]) * inv_ell2;
            const float k = ((dim_over_ell2 * g - 3.0f * r2 * inv2 * q25)
                             + cross * g) + dssa[p] * sq;
            // +inf rows stay +inf (their loads were clamped to a real row => k finite)
            const float o = objr[p] + (2.0f * k - w * lpr[p]);
            objr[p] = o;
            const unsigned long long pk = pack_min(o, (unsigned)(tid + p * T));
            if (pk < lbest) lbest = pk;
        }

        #pragma unroll
        for (int off = 32; off >= 1; off >>= 1) {
            unsigned long long o = shfl_down_u64(lbest, off);
            lbest = (o < lbest) ? o : lbest;
        }
        if (lane == 0) red_scratch[wave] = lbest;
        __syncthreads();
        if (threadIdx.x == 0) {
            unsigned long long r = red_scratch[0];
            #pragma unroll
            for (int i = 1; i < (BLOCK / 64); ++i) {
                unsigned long long o = red_scratch[i];
                r = (o < r) ? o : r;
            }
            post_slot(slots, r, t);
        }
    }

    // -------- final argmin -> out[m-1] ----------------------------------------
    {
        gather_stage(slots + (size_t)((m - 1) & 1) * GRID, m - 1, &gmin_sh,
                     X4, S4, xi4, si4);
        if (blockIdx.x == 0 && threadIdx.x == 0)
            out[m - 1] = (int)(gmin_sh & 0xFFFFFull);
    }
}

extern "C" void kernel_launch(void* const* d_in, const int* in_sizes, int n_in,
                              void* d_out, int out_size, void* d_ws, size_t ws_size,
                              hipStream_t stream) {
    const float* x        = (const float*)d_in[0];
    const float* log_p    = (const float*)d_in[1];
    const float* score_p  = (const float*)d_in[2];
    const float* laplace  = (const float*)d_in[3];
    const float* ls_ptr   = (const float*)d_in[4];

    int* out = (int*)d_out;
    int N = in_sizes[1];            // log_p has N elements
    int m = out_size;

    unsigned long long* slots = (unsigned long long*)d_ws;  // 2*GRID u64 = 4 KB

    // Single deterministic path: plain launch, identical on every call
    // (correctness call, graph capture, tripwire). 152 KB LDS => exactly
    // 1 block/CU => 256 blocks on 256 CUs are structurally co-resident.
    stein_thin_persist<<<dim3(GRID), dim3(BLOCK), 0, stream>>>(
        x, log_p, score_p, laplace, ls_ptr, out, slots, N, m);
}